// Round 1
// baseline (658.388 us; speedup 1.0000x reference)
//
#include <hip/hip_runtime.h>
#include <math.h>

#define BB 2
#define NN 1024
#define KNN 32
#define PP 65
#define NRBF 16
#define EC 128
#define TE 16

// ---------------- kernel 1: atoms15 ----------------
__global__ __launch_bounds__(256) void k_atoms(
    const float* __restrict__ coords, const float* __restrict__ mask,
    const float* __restrict__ noise, float* __restrict__ atoms15)
{
    int idx = blockIdx.x * blockDim.x + threadIdx.x;
    if (idx >= BB * NN) return;
    const float* c  = coords + (size_t)idx * 42;
    const float* nz = noise  + (size_t)idx * 42;
    const float* m  = mask   + (size_t)idx * 14;

    float X[14][3];
    float x1[3];
#pragma unroll
    for (int d = 0; d < 3; d++) x1[d] = c[3 + d] + nz[3 + d];
#pragma unroll
    for (int a = 0; a < 14; a++) {
        bool mm = m[a] > 0.0f;
#pragma unroll
        for (int d = 0; d < 3; d++) {
            float v = c[a * 3 + d] + nz[a * 3 + d];
            X[a][d] = mm ? v : x1[d];
        }
    }
    float bv[3], cv[3], av[3], cb[3];
#pragma unroll
    for (int d = 0; d < 3; d++) { bv[d] = X[1][d] - X[0][d]; cv[d] = X[2][d] - X[1][d]; }
    av[0] = bv[1] * cv[2] - bv[2] * cv[1];
    av[1] = bv[2] * cv[0] - bv[0] * cv[2];
    av[2] = bv[0] * cv[1] - bv[1] * cv[0];
#pragma unroll
    for (int d = 0; d < 3; d++)
        cb[d] = -0.58273431f * av[d] + 0.56802827f * bv[d] - 0.54067466f * cv[d] + X[1][d];

    float* o = atoms15 + (size_t)idx * 45;
#pragma unroll
    for (int a = 0; a < 4; a++)
#pragma unroll
        for (int d = 0; d < 3; d++) o[a * 3 + d] = X[a][d];
#pragma unroll
    for (int d = 0; d < 3; d++) o[4 * 3 + d] = cb[d];
#pragma unroll
    for (int a = 0; a < 10; a++)
#pragma unroll
        for (int d = 0; d < 3; d++) o[(5 + a) * 3 + d] = X[4 + a][d];
}

// ---------------- kernel 2: KNN ----------------
__global__ __launch_bounds__(256) void k_knn(
    const float* __restrict__ atoms15, const float* __restrict__ cond,
    float* __restrict__ out_idx_f, float* __restrict__ out_d, int* __restrict__ eidx)
{
    __shared__ float Dadj[NN];
    __shared__ float m2s[NN];
    __shared__ float redv[4];
    __shared__ int   redi[4];
    __shared__ float rmax[4];

    int row = blockIdx.x;
    int b = row >> 10, i = row & (NN - 1);
    int t = threadIdx.x;
    const float* ab = atoms15 + (size_t)b * NN * 45;
    float cax = ab[(size_t)i * 45 + 3];
    float cay = ab[(size_t)i * 45 + 4];
    float caz = ab[(size_t)i * 45 + 5];
    float mi = cond[(size_t)row * 14 + 1];

    float lmax = -1e30f;
    for (int j = t; j < NN; j += 256) {
        float dx = cax - ab[(size_t)j * 45 + 3];
        float dy = cay - ab[(size_t)j * 45 + 4];
        float dz = caz - ab[(size_t)j * 45 + 5];
        float mj = cond[((size_t)b * NN + j) * 14 + 1];
        float m2 = mi * mj;
        float D = m2 * sqrtf(dx * dx + dy * dy + dz * dz + 1e-6f);
        Dadj[j] = D; m2s[j] = m2;
        lmax = fmaxf(lmax, D);
    }
#pragma unroll
    for (int off = 32; off > 0; off >>= 1) lmax = fmaxf(lmax, __shfl_xor(lmax, off));
    int wv = t >> 6, ln = t & 63;
    if (ln == 0) rmax[wv] = lmax;
    __syncthreads();
    float Dmax = fmaxf(fmaxf(rmax[0], rmax[1]), fmaxf(rmax[2], rmax[3]));
    for (int j = t; j < NN; j += 256) Dadj[j] += (1.0f - m2s[j]) * Dmax;
    __syncthreads();

    for (int k = 0; k < KNN; k++) {
        float bvv = 1e30f; int bii = NN;
        for (int j = t; j < NN; j += 256) {
            float v = Dadj[j];
            if (v < bvv || (v == bvv && j < bii)) { bvv = v; bii = j; }
        }
#pragma unroll
        for (int off = 1; off < 64; off <<= 1) {
            float ov = __shfl_xor(bvv, off);
            int   oi = __shfl_xor(bii, off);
            if (ov < bvv || (ov == bvv && oi < bii)) { bvv = ov; bii = oi; }
        }
        if (ln == 0) { redv[wv] = bvv; redi[wv] = bii; }
        __syncthreads();
        if (t == 0) {
            float bv2 = redv[0]; int bi2 = redi[0];
            for (int w = 1; w < 4; w++) {
                if (redv[w] < bv2 || (redv[w] == bv2 && redi[w] < bi2)) { bv2 = redv[w]; bi2 = redi[w]; }
            }
            out_idx_f[(size_t)row * KNN + k] = (float)bi2;
            out_d  [(size_t)row * KNN + k] = bv2;
            eidx   [(size_t)row * KNN + k] = bi2;
            Dadj[bi2] = 1e30f;
        }
        __syncthreads();
    }
}

// ---------------- kernel 3: edge features + GEMV + LayerNorm ----------------
__global__ __launch_bounds__(256) void k_edge(
    const float* __restrict__ atoms15, const int* __restrict__ eidx,
    const int* __restrict__ resi, const int* __restrict__ asym,
    const float* __restrict__ tbonds, const int* __restrict__ islig,
    const float* __restrict__ posW, const float* __restrict__ posb,
    const float* __restrict__ edgeW, const float* __restrict__ gamma_,
    const float* __restrict__ beta_, float* __restrict__ outE)
{
    __shared__ __attribute__((aligned(16))) float fbuf[2][TE][NRBF];
    __shared__ __attribute__((aligned(16))) float epos[TE][NRBF];
    __shared__ float Arow[48];
    __shared__ float Brow[TE][48];
    __shared__ float Dp[TE][PP];
    __shared__ float tbv[TE];
    __shared__ int   nb[TE];

    int blk = blockIdx.x;
    int half = blk & 1, row = blk >> 1;
    int b = row >> 10, i = row & (NN - 1);
    int t = threadIdx.x;

    if (t < TE) nb[t] = eidx[(size_t)row * KNN + half * TE + t];
    __syncthreads();

    if (t < 45) Arow[t] = atoms15[((size_t)(b * NN + i)) * 45 + t];
    for (int x = t; x < TE * 45; x += 256) {
        int e = x / 45, r = x - e * 45;
        Brow[e][r] = atoms15[((size_t)(b * NN) + nb[e]) * 45 + r];
    }
    {   // positional features (exactly 256 tasks)
        int e = t >> 4, r = t & 15;
        int j = nb[e];
        int off = resi[b * NN + i] - resi[b * NN + j];
        bool same = (asym[b * NN + i] == asym[b * NN + j]);
        int d = same ? min(max(off + 32, 0), 64) : 65;
        epos[e][r] = posW[d * 16 + r] + posb[r];
    }
    if (t < TE) {
        int j = nb[t];
        bool lg = (islig[b * NN + i] != 0) || (islig[b * NN + j] != 0);
        tbv[t] = lg ? tbonds[((size_t)(b * NN + i)) * NN + j] : 0.0f;
    }
    __syncthreads();

    // pair distances: 16 edges x 65 pairs
    for (int x = t; x < TE * PP; x += 256) {
        int e = x / PP, p = x - e * PP;
        int s, dd;
        if (p < 25) { s = p / 5; dd = p - s * 5; }
        else { int q = p - 25; s = q / 10; dd = 5 + (q - s * 10); }
        float dx = Arow[s * 3 + 0] - Brow[e][dd * 3 + 0];
        float dy = Arow[s * 3 + 1] - Brow[e][dd * 3 + 1];
        float dz = Arow[s * 3 + 2] - Brow[e][dd * 3 + 2];
        Dp[e][p] = sqrtf(dx * dx + dy * dy + dz * dz + 1e-6f);
    }
    __syncthreads();

    // stage RBF chunk 0
    {
        int e = t >> 4, r = t & 15;
        float u = (Dp[e][0] - (2.0f + (float)r * (20.0f / 15.0f))) * 0.8f;
        fbuf[0][e][r] = expf(-u * u);
    }
    __syncthreads();

    int c2 = t & 63, eg = t >> 6;
    int e0 = eg * 4;
    float acc[4][2] = {};
    const float* wbase = edgeW + c2 * 2;

    for (int p = 0; p < PP; p++) {
        if (p + 1 < PP) {
            int e = t >> 4, r = t & 15;
            float u = (Dp[e][p + 1] - (2.0f + (float)r * (20.0f / 15.0f))) * 0.8f;
            fbuf[(p + 1) & 1][e][r] = expf(-u * u);
        }
        int pb = p & 1;
        const float* wr = wbase + (size_t)(16 + p * 16) * EC;
#pragma unroll
        for (int r4 = 0; r4 < NRBF; r4 += 4) {
            float4 f0 = *(const float4*)&fbuf[pb][e0 + 0][r4];
            float4 f1 = *(const float4*)&fbuf[pb][e0 + 1][r4];
            float4 f2 = *(const float4*)&fbuf[pb][e0 + 2][r4];
            float4 f3 = *(const float4*)&fbuf[pb][e0 + 3][r4];
#pragma unroll
            for (int rr = 0; rr < 4; rr++) {
                float2 w = *(const float2*)(wr + (size_t)(r4 + rr) * EC);
                float fa = (&f0.x)[rr], fb_ = (&f1.x)[rr], fc = (&f2.x)[rr], fd = (&f3.x)[rr];
                acc[0][0] += fa  * w.x; acc[0][1] += fa  * w.y;
                acc[1][0] += fb_ * w.x; acc[1][1] += fb_ * w.y;
                acc[2][0] += fc  * w.x; acc[2][1] += fc  * w.y;
                acc[3][0] += fd  * w.x; acc[3][1] += fd  * w.y;
            }
        }
        __syncthreads();
    }

    // positional features (f = 0..15)
    {
        const float* wr = wbase;
#pragma unroll
        for (int r4 = 0; r4 < NRBF; r4 += 4) {
            float4 f0 = *(const float4*)&epos[e0 + 0][r4];
            float4 f1 = *(const float4*)&epos[e0 + 1][r4];
            float4 f2 = *(const float4*)&epos[e0 + 2][r4];
            float4 f3 = *(const float4*)&epos[e0 + 3][r4];
#pragma unroll
            for (int rr = 0; rr < 4; rr++) {
                float2 w = *(const float2*)(wr + (size_t)(r4 + rr) * EC);
                float fa = (&f0.x)[rr], fb_ = (&f1.x)[rr], fc = (&f2.x)[rr], fd = (&f3.x)[rr];
                acc[0][0] += fa  * w.x; acc[0][1] += fa  * w.y;
                acc[1][0] += fb_ * w.x; acc[1][1] += fb_ * w.y;
                acc[2][0] += fc  * w.x; acc[2][1] += fc  * w.y;
                acc[3][0] += fd  * w.x; acc[3][1] += fd  * w.y;
            }
        }
        // token-bond feature (f = 1056)
        float2 wt = *(const float2*)(edgeW + (size_t)1056 * EC + c2 * 2);
#pragma unroll
        for (int e = 0; e < 4; e++) {
            float tv = tbv[e0 + e];
            acc[e][0] += tv * wt.x; acc[e][1] += tv * wt.y;
        }
    }

    // LayerNorm + store
    float2 g  = *(const float2*)(gamma_ + c2 * 2);
    float2 be = *(const float2*)(beta_  + c2 * 2);
#pragma unroll
    for (int e = 0; e < 4; e++) {
        float s = acc[e][0] + acc[e][1];
        float q = acc[e][0] * acc[e][0] + acc[e][1] * acc[e][1];
#pragma unroll
        for (int off = 1; off < 64; off <<= 1) {
            s += __shfl_xor(s, off);
            q += __shfl_xor(q, off);
        }
        float mu  = s * (1.0f / 128.0f);
        float var = q * (1.0f / 128.0f) - mu * mu;
        float rstd = rsqrtf(var + 1e-5f);
        float o0 = (acc[e][0] - mu) * rstd * g.x + be.x;
        float o1 = (acc[e][1] - mu) * rstd * g.y + be.y;
        size_t eg_global = (size_t)row * KNN + half * TE + e0 + e;
        *(float2*)(outE + eg_global * EC + c2 * 2) = make_float2(o0, o1);
    }
}

extern "C" void kernel_launch(void* const* d_in, const int* in_sizes, int n_in,
                              void* d_out, int out_size, void* d_ws, size_t ws_size,
                              hipStream_t stream)
{
    const float* coords = (const float*)d_in[0];
    const float* cond   = (const float*)d_in[1];
    const float* noise  = (const float*)d_in[2];
    const int*   resi   = (const int*)d_in[3];
    const int*   asym   = (const int*)d_in[4];
    const float* tbonds = (const float*)d_in[5];
    const int*   islig  = (const int*)d_in[6];
    const float* posW   = (const float*)d_in[7];
    const float* posb   = (const float*)d_in[8];
    const float* edgeW  = (const float*)d_in[9];
    const float* gamma_ = (const float*)d_in[10];
    const float* beta_  = (const float*)d_in[11];

    float* outE   = (float*)d_out;                          // (B,N,K,128)
    float* outIdx = outE + (size_t)BB * NN * KNN * EC;      // (B,N,K) as float
    float* outD   = outIdx + (size_t)BB * NN * KNN;         // (B,N,K)

    float* atoms15 = (float*)d_ws;                          // B*N*45 floats
    int*   eidx    = (int*)((char*)d_ws + (size_t)BB * NN * 45 * sizeof(float));

    k_atoms<<<(BB * NN + 255) / 256, 256, 0, stream>>>(coords, cond, noise, atoms15);
    k_knn<<<BB * NN, 256, 0, stream>>>(atoms15, cond, outIdx, outD, eidx);
    k_edge<<<BB * NN * 2, 256, 0, stream>>>(atoms15, eidx, resi, asym, tbonds, islig,
                                            posW, posb, edgeW, gamma_, beta_, outE);
}

// Round 8
// 245.617 us; speedup vs baseline: 2.6805x; 2.6805x over previous
//
#include <hip/hip_runtime.h>
#include <math.h>

#define BB 2
#define NN 1024
#define KNN 32
#define PP 65
#define NRBF 16
#define EC 128
#define KPAD 1088            // 17 chunks * 64
#define NCHUNK 17
#define NKT 34               // KPAD / 32 MFMA k-steps

typedef __attribute__((ext_vector_type(8))) short bf16x8;
typedef __attribute__((ext_vector_type(4))) float f32x4;

__device__ __forceinline__ ushort f2bf(float f) {
    union { float f; unsigned u; } v; v.f = f;
    unsigned r = v.u + 0x7fffu + ((v.u >> 16) & 1u);
    return (ushort)(r >> 16);
}

// ---------------- kernel 1: atoms15 ----------------
__global__ __launch_bounds__(256) void k_atoms(
    const float* __restrict__ coords, const float* __restrict__ mask,
    const float* __restrict__ noise, float* __restrict__ atoms15)
{
    int idx = blockIdx.x * blockDim.x + threadIdx.x;
    if (idx >= BB * NN) return;
    const float* c  = coords + (size_t)idx * 42;
    const float* nz = noise  + (size_t)idx * 42;
    const float* m  = mask   + (size_t)idx * 14;

    float X[14][3];
    float x1[3];
#pragma unroll
    for (int d = 0; d < 3; d++) x1[d] = c[3 + d] + nz[3 + d];
#pragma unroll
    for (int a = 0; a < 14; a++) {
        bool mm = m[a] > 0.0f;
#pragma unroll
        for (int d = 0; d < 3; d++) {
            float v = c[a * 3 + d] + nz[a * 3 + d];
            X[a][d] = mm ? v : x1[d];
        }
    }
    float bv[3], cv[3], av[3], cb[3];
#pragma unroll
    for (int d = 0; d < 3; d++) { bv[d] = X[1][d] - X[0][d]; cv[d] = X[2][d] - X[1][d]; }
    av[0] = bv[1] * cv[2] - bv[2] * cv[1];
    av[1] = bv[2] * cv[0] - bv[0] * cv[2];
    av[2] = bv[0] * cv[1] - bv[1] * cv[0];
#pragma unroll
    for (int d = 0; d < 3; d++)
        cb[d] = -0.58273431f * av[d] + 0.56802827f * bv[d] - 0.54067466f * cv[d] + X[1][d];

    float* o = atoms15 + (size_t)idx * 45;
#pragma unroll
    for (int a = 0; a < 4; a++)
#pragma unroll
        for (int d = 0; d < 3; d++) o[a * 3 + d] = X[a][d];
#pragma unroll
    for (int d = 0; d < 3; d++) o[4 * 3 + d] = cb[d];
#pragma unroll
    for (int a = 0; a < 10; a++)
#pragma unroll
        for (int d = 0; d < 3; d++) o[(5 + a) * 3 + d] = X[4 + a][d];
}

// ---------------- kernel 2: KNN (Round-1 hardware-proven version) ----------------
__global__ __launch_bounds__(256) void k_knn(
    const float* __restrict__ atoms15, const float* __restrict__ cond,
    float* __restrict__ out_idx_f, float* __restrict__ out_d, int* __restrict__ eidx)
{
    __shared__ float Dadj[NN];
    __shared__ float m2s[NN];
    __shared__ float redv[4];
    __shared__ int   redi[4];
    __shared__ float rmax[4];

    int row = blockIdx.x;
    int b = row >> 10, i = row & (NN - 1);
    int t = threadIdx.x;
    const float* ab = atoms15 + (size_t)b * NN * 45;
    float cax = ab[(size_t)i * 45 + 3];
    float cay = ab[(size_t)i * 45 + 4];
    float caz = ab[(size_t)i * 45 + 5];
    float mi = cond[(size_t)row * 14 + 1];

    float lmax = -1e30f;
    for (int j = t; j < NN; j += 256) {
        float dx = cax - ab[(size_t)j * 45 + 3];
        float dy = cay - ab[(size_t)j * 45 + 4];
        float dz = caz - ab[(size_t)j * 45 + 5];
        float mj = cond[((size_t)b * NN + j) * 14 + 1];
        float m2 = mi * mj;
        float D = m2 * sqrtf(dx * dx + dy * dy + dz * dz + 1e-6f);
        Dadj[j] = D; m2s[j] = m2;
        lmax = fmaxf(lmax, D);
    }
#pragma unroll
    for (int off = 32; off > 0; off >>= 1) lmax = fmaxf(lmax, __shfl_xor(lmax, off));
    int wv = t >> 6, ln = t & 63;
    if (ln == 0) rmax[wv] = lmax;
    __syncthreads();
    float Dmax = fmaxf(fmaxf(rmax[0], rmax[1]), fmaxf(rmax[2], rmax[3]));
    for (int j = t; j < NN; j += 256) Dadj[j] += (1.0f - m2s[j]) * Dmax;
    __syncthreads();

    for (int k = 0; k < KNN; k++) {
        float bvv = 1e30f; int bii = NN;
        for (int j = t; j < NN; j += 256) {
            float v = Dadj[j];
            if (v < bvv || (v == bvv && j < bii)) { bvv = v; bii = j; }
        }
#pragma unroll
        for (int off = 1; off < 64; off <<= 1) {
            float ov = __shfl_xor(bvv, off);
            int   oi = __shfl_xor(bii, off);
            if (ov < bvv || (ov == bvv && oi < bii)) { bvv = ov; bii = oi; }
        }
        if (ln == 0) { redv[wv] = bvv; redi[wv] = bii; }
        __syncthreads();
        if (t == 0) {
            float bv2 = redv[0]; int bi2 = redi[0];
            for (int w = 1; w < 4; w++) {
                if (redv[w] < bv2 || (redv[w] == bv2 && redi[w] < bi2)) { bv2 = redv[w]; bi2 = redi[w]; }
            }
            out_idx_f[(size_t)row * KNN + k] = (float)bi2;
            out_d  [(size_t)row * KNN + k] = bv2;
            eidx   [(size_t)row * KNN + k] = bi2;
            Dadj[bi2] = 1e30f;
        }
        __syncthreads();
    }
}

// ---------------- kernel 2.5: W -> bf16 fragment layout ----------------
// Wfrag[kt][n16][lane][8] : k = kt*32 + (lane>>4)*8 + j, col = n16*16 + (lane&15)
__global__ __launch_bounds__(256) void k_wprep(const float* __restrict__ W,
                                               ushort* __restrict__ wf)
{
    int x = blockIdx.x * 256 + threadIdx.x;
    if (x >= NKT * 8 * 64) return;
    int l = x & 63;
    int n16 = (x >> 6) & 7;
    int kt = x >> 9;
    int col = n16 * 16 + (l & 15);
    int kb  = kt * 32 + (l >> 4) * 8;
    ushort v[8];
#pragma unroll
    for (int j = 0; j < 8; j++) {
        int k = kb + j;
        float f = (k < 1057) ? W[(size_t)k * EC + col] : 0.0f;
        v[j] = f2bf(f);
    }
    *(uint4*)&wf[(size_t)x * 8] = *(uint4*)&v[0];
}

// ---------------- kernel 3: MFMA edge GEMM + LayerNorm ----------------
__global__ __launch_bounds__(256) void k_edge(
    const float* __restrict__ atoms15, const int* __restrict__ eidx,
    const int* __restrict__ resi, const int* __restrict__ asym,
    const float* __restrict__ tbonds, const int* __restrict__ islig,
    const float* __restrict__ posW, const float* __restrict__ posb,
    const ushort* __restrict__ wfrag, const float* __restrict__ gamma_,
    const float* __restrict__ beta_, float* __restrict__ outE)
{
    __shared__ int   nb[64];
    __shared__ float tbv[64];
    __shared__ float Crow[2][45];
    __shared__ float Brow[64][45];
    __shared__ float epos[64][16];
    __shared__ float Dp[64][PP];
    __shared__ __attribute__((aligned(16))) ushort F[64][72];   // padded: stride 144B
    __shared__ float part[2][64][2];

    int blk = blockIdx.x;          // 1024 blocks, 2 KNN rows each
    int row0 = blk * 2;
    int b = row0 >> 10;
    int t = threadIdx.x;

    if (t < 64) nb[t] = eidx[(size_t)row0 * KNN + t];
    __syncthreads();

    if (t < 90) {
        int e = t / 45, r = t - e * 45;
        Crow[e][r] = atoms15[((size_t)(row0 + e)) * 45 + r];
    }
    {   // neighbor atoms: thread t -> edge t&63, atom chunk (t>>6)*12..+11
        int e = t & 63;
        const float* src = atoms15 + ((size_t)(b * NN) + nb[e]) * 45;
#pragma unroll
        for (int q = 0; q < 12; q++) {
            int r = (t >> 6) * 12 + q;
            if (r < 45) Brow[e][r] = src[r];
        }
    }
    for (int x = t; x < 64 * 16; x += 256) {   // positional features
        int e = x >> 4, r = x & 15;
        int ri = row0 + (e >> 5);
        int ii = ri & (NN - 1);
        int j = nb[e];
        int off = resi[(b << 10) + ii] - resi[(b << 10) + j];
        bool same = (asym[(b << 10) + ii] == asym[(b << 10) + j]);
        int d = same ? min(max(off + 32, 0), 64) : 65;
        epos[e][r] = posW[d * 16 + r] + posb[r];
    }
    if (t < 64) {
        int ri = row0 + (t >> 5);
        int ii = ri & (NN - 1);
        int j = nb[t];
        bool lg = (islig[(b << 10) + ii] != 0) || (islig[(b << 10) + j] != 0);
        tbv[t] = lg ? tbonds[((size_t)((b << 10) + ii)) * NN + j] : 0.0f;
    }
    __syncthreads();

    // pair distances: 64 edges x 65 pairs
    for (int x = t; x < 64 * PP; x += 256) {
        int e = x / PP, p = x - e * PP;
        int s, dd;
        if (p < 25) { s = p / 5; dd = p - s * 5; }
        else { int q = p - 25; s = q / 10; dd = 5 + (q - s * 10); }
        int cc = e >> 5;
        float dx = Crow[cc][s * 3 + 0] - Brow[e][dd * 3 + 0];
        float dy = Crow[cc][s * 3 + 1] - Brow[e][dd * 3 + 1];
        float dz = Crow[cc][s * 3 + 2] - Brow[e][dd * 3 + 2];
        Dp[e][p] = sqrtf(dx * dx + dy * dy + dz * dz + 1e-6f);
    }
    __syncthreads();

    const int l  = t & 63;
    const int w  = t >> 6;
    const int wm = w >> 1, wn = w & 1;
    const int lc = l & 15, g = l >> 4;

    f32x4 acc[2][4] = {};

    for (int c = 0; c < NCHUNK; c++) {
        // ---- stage 64 features x 64 edges into F (bf16) ----
        {
            int e = l;          // edge = lane
            int fb = w;         // feature block = wave (wave-uniform branch)
            float vals[16];
            if (c == 0 && fb == 0) {
#pragma unroll
                for (int i2 = 0; i2 < 16; i2++) vals[i2] = epos[e][i2];
            } else if (c == 16 && fb >= 2) {
#pragma unroll
                for (int i2 = 0; i2 < 16; i2++) vals[i2] = 0.0f;
                if (fb == 2) vals[0] = tbv[e];
            } else {
                int p = 4 * c + fb - 1;
                float d = Dp[e][p];
#pragma unroll
                for (int i2 = 0; i2 < 16; i2++) {
                    float u = (d - (2.0f + (float)i2 * (20.0f / 15.0f))) * 0.8f;
                    vals[i2] = __expf(-u * u);
                }
            }
            ushort us[16];
#pragma unroll
            for (int i2 = 0; i2 < 16; i2++) us[i2] = f2bf(vals[i2]);
            *(uint4*)&F[e][fb * 16]     = *(uint4*)&us[0];
            *(uint4*)&F[e][fb * 16 + 8] = *(uint4*)&us[8];
        }
        __syncthreads();

        // ---- MFMA over the 64-feature chunk (2 k-steps of 32) ----
#pragma unroll
        for (int ks = 0; ks < 2; ks++) {
            bf16x8 a0 = *(const bf16x8*)&F[wm * 32 + lc][ks * 32 + 8 * g];
            bf16x8 a1 = *(const bf16x8*)&F[wm * 32 + 16 + lc][ks * 32 + 8 * g];
            int kt = c * 2 + ks;
#pragma unroll
            for (int ni = 0; ni < 4; ni++) {
                bf16x8 bfg = *(const bf16x8*)&wfrag[(((size_t)kt * 8 + wn * 4 + ni) * 64 + l) * 8];
                acc[0][ni] = __builtin_amdgcn_mfma_f32_16x16x32_bf16(a0, bfg, acc[0][ni], 0, 0, 0);
                acc[1][ni] = __builtin_amdgcn_mfma_f32_16x16x32_bf16(a1, bfg, acc[1][ni], 0, 0, 0);
            }
        }
        __syncthreads();
    }

    // ---- LayerNorm epilogue ----
    float gv[4], bev[4];
#pragma unroll
    for (int ni = 0; ni < 4; ni++) {
        int col = wn * 64 + ni * 16 + lc;
        gv[ni]  = gamma_[col];
        bev[ni] = beta_[col];
    }
#pragma unroll
    for (int mi = 0; mi < 2; mi++)
#pragma unroll
        for (int reg = 0; reg < 4; reg++) {
            float s = 0.0f, q = 0.0f;
#pragma unroll
            for (int ni = 0; ni < 4; ni++) {
                float v = acc[mi][ni][reg];
                s += v; q += v * v;
            }
#pragma unroll
            for (int m = 1; m < 16; m <<= 1) {
                s += __shfl_xor(s, m);
                q += __shfl_xor(q, m);
            }
            int srow = wm * 32 + mi * 16 + g * 4 + reg;
            if (lc == 0) { part[wn][srow][0] = s; part[wn][srow][1] = q; }
        }
    __syncthreads();
#pragma unroll
    for (int mi = 0; mi < 2; mi++)
#pragma unroll
        for (int reg = 0; reg < 4; reg++) {
            int srow = wm * 32 + mi * 16 + g * 4 + reg;
            float s = part[0][srow][0] + part[1][srow][0];
            float q = part[0][srow][1] + part[1][srow][1];
            float mu  = s * (1.0f / 128.0f);
            float var = q * (1.0f / 128.0f) - mu * mu;
            float rstd = rsqrtf(var + 1e-5f);
            size_t obase = ((size_t)blk * 64 + srow) * EC;
#pragma unroll
            for (int ni = 0; ni < 4; ni++) {
                float v = (acc[mi][ni][reg] - mu) * rstd * gv[ni] + bev[ni];
                outE[obase + wn * 64 + ni * 16 + lc] = v;
            }
        }
}

extern "C" void kernel_launch(void* const* d_in, const int* in_sizes, int n_in,
                              void* d_out, int out_size, void* d_ws, size_t ws_size,
                              hipStream_t stream)
{
    const float* coords = (const float*)d_in[0];
    const float* cond   = (const float*)d_in[1];
    const float* noise  = (const float*)d_in[2];
    const int*   resi   = (const int*)d_in[3];
    const int*   asym   = (const int*)d_in[4];
    const float* tbonds = (const float*)d_in[5];
    const int*   islig  = (const int*)d_in[6];
    const float* posW   = (const float*)d_in[7];
    const float* posb   = (const float*)d_in[8];
    const float* edgeW  = (const float*)d_in[9];
    const float* gamma_ = (const float*)d_in[10];
    const float* beta_  = (const float*)d_in[11];

    float* outE   = (float*)d_out;                          // (B,N,K,128)
    float* outIdx = outE + (size_t)BB * NN * KNN * EC;      // (B,N,K) as float
    float* outD   = outIdx + (size_t)BB * NN * KNN;         // (B,N,K)

    float*  atoms15 = (float*)d_ws;                                          // 368640 B
    int*    eidx    = (int*)((char*)d_ws + 368640);                          // 262144 B
    ushort* wfrag   = (ushort*)((char*)d_ws + 368640 + 262144);              // 278528 B

    k_wprep<<<(NKT * 8 * 64 + 255) / 256, 256, 0, stream>>>(edgeW, wfrag);
    k_atoms<<<(BB * NN + 255) / 256, 256, 0, stream>>>(coords, cond, noise, atoms15);
    k_knn<<<BB * NN, 256, 0, stream>>>(atoms15, cond, outIdx, outD, eidx);
    k_edge<<<BB * NN / 2, 256, 0, stream>>>(atoms15, eidx, resi, asym, tbonds, islig,
                                            posW, posb, wfrag, gamma_, beta_, outE);
}

// Round 9
// 233.815 us; speedup vs baseline: 2.8159x; 1.0505x over previous
//
#include <hip/hip_runtime.h>
#include <math.h>

#define BB 2
#define NN 1024
#define KNN 32
#define PP 65
#define NRBF 16
#define EC 128
#define KPAD 1088            // 17 chunks * 64
#define NCHUNK 17
#define NKT 34               // KPAD / 32 MFMA k-steps

typedef __attribute__((ext_vector_type(8))) short bf16x8;
typedef __attribute__((ext_vector_type(4))) float f32x4;

__device__ __forceinline__ ushort f2bf(float f) {
    union { float f; unsigned u; } v; v.f = f;
    unsigned r = v.u + 0x7fffu + ((v.u >> 16) & 1u);
    return (ushort)(r >> 16);
}

// ---------------- kernel 1: atoms15 ----------------
__global__ __launch_bounds__(256) void k_atoms(
    const float* __restrict__ coords, const float* __restrict__ mask,
    const float* __restrict__ noise, float* __restrict__ atoms15)
{
    int idx = blockIdx.x * blockDim.x + threadIdx.x;
    if (idx >= BB * NN) return;
    const float* c  = coords + (size_t)idx * 42;
    const float* nz = noise  + (size_t)idx * 42;
    const float* m  = mask   + (size_t)idx * 14;

    float X[14][3];
    float x1[3];
#pragma unroll
    for (int d = 0; d < 3; d++) x1[d] = c[3 + d] + nz[3 + d];
#pragma unroll
    for (int a = 0; a < 14; a++) {
        bool mm = m[a] > 0.0f;
#pragma unroll
        for (int d = 0; d < 3; d++) {
            float v = c[a * 3 + d] + nz[a * 3 + d];
            X[a][d] = mm ? v : x1[d];
        }
    }
    float bv[3], cv[3], av[3], cb[3];
#pragma unroll
    for (int d = 0; d < 3; d++) { bv[d] = X[1][d] - X[0][d]; cv[d] = X[2][d] - X[1][d]; }
    av[0] = bv[1] * cv[2] - bv[2] * cv[1];
    av[1] = bv[2] * cv[0] - bv[0] * cv[2];
    av[2] = bv[0] * cv[1] - bv[1] * cv[0];
#pragma unroll
    for (int d = 0; d < 3; d++)
        cb[d] = -0.58273431f * av[d] + 0.56802827f * bv[d] - 0.54067466f * cv[d] + X[1][d];

    float* o = atoms15 + (size_t)idx * 45;
#pragma unroll
    for (int a = 0; a < 4; a++)
#pragma unroll
        for (int d = 0; d < 3; d++) o[a * 3 + d] = X[a][d];
#pragma unroll
    for (int d = 0; d < 3; d++) o[4 * 3 + d] = cb[d];
#pragma unroll
    for (int a = 0; a < 10; a++)
#pragma unroll
        for (int d = 0; d < 3; d++) o[(5 + a) * 3 + d] = X[4 + a][d];
}

// ---------------- kernel 2: KNN ----------------
// Distance phase identical to the hardware-proven version; selection is
// register-resident per-wave top-32 (no LDS writes in the argmin loop)
// + single wave-0 merge. Barriers: 66 -> 3.
__global__ __launch_bounds__(256) void k_knn(
    const float* __restrict__ atoms15, const float* __restrict__ cond,
    float* __restrict__ out_idx_f, float* __restrict__ out_d, int* __restrict__ eidx)
{
    __shared__ float Dadj[NN];
    __shared__ float m2s[NN];
    __shared__ float rmax[4];
    __shared__ float candv[128];
    __shared__ int   candj[128];

    int row = blockIdx.x;
    int b = row >> 10, i = row & (NN - 1);
    int t = threadIdx.x;
    int ln = t & 63, wv = t >> 6;
    const float* ab = atoms15 + (size_t)b * NN * 45;
    float cax = ab[(size_t)i * 45 + 3];
    float cay = ab[(size_t)i * 45 + 4];
    float caz = ab[(size_t)i * 45 + 5];
    float mi = cond[(size_t)row * 14 + 1];

    float lmax = -1e30f;
    for (int j = t; j < NN; j += 256) {
        float dx = cax - ab[(size_t)j * 45 + 3];
        float dy = cay - ab[(size_t)j * 45 + 4];
        float dz = caz - ab[(size_t)j * 45 + 5];
        float mj = cond[((size_t)b * NN + j) * 14 + 1];
        float m2 = mi * mj;
        float D = m2 * sqrtf(dx * dx + dy * dy + dz * dz + 1e-6f);
        Dadj[j] = D; m2s[j] = m2;
        lmax = fmaxf(lmax, D);
    }
#pragma unroll
    for (int off = 32; off > 0; off >>= 1) lmax = fmaxf(lmax, __shfl_xor(lmax, off));
    if (ln == 0) rmax[wv] = lmax;
    __syncthreads();
    float Dmax = fmaxf(fmaxf(rmax[0], rmax[1]), fmaxf(rmax[2], rmax[3]));
    for (int j = t; j < NN; j += 256) Dadj[j] += (1.0f - m2s[j]) * Dmax;
    __syncthreads();

    // ---- phase 1: per-wave top-32 of partition [wv*256, wv*256+256) ----
    const int base = wv * 256 + ln;
    float v0 = Dadj[base];
    float v1 = Dadj[base + 64];
    float v2 = Dadj[base + 128];
    float v3 = Dadj[base + 192];

    float selv = 0.0f; int seli = 0;
    for (int k = 0; k < KNN; k++) {
        // within-lane argmin; strict < keeps the lower q (= lower j) on ties
        float bv = v0; int bj = base;
        if (v1 < bv) { bv = v1; bj = base + 64;  }
        if (v2 < bv) { bv = v2; bj = base + 128; }
        if (v3 < bv) { bv = v3; bj = base + 192; }
#pragma unroll
        for (int off = 1; off < 64; off <<= 1) {
            float ov = __shfl_xor(bv, off);
            int   oj = __shfl_xor(bj, off);
            if (ov < bv || (ov == bv && oj < bj)) { bv = ov; bj = oj; }
        }
        if (ln == k) { selv = bv; seli = bj; }
        // register-predicated eviction (exactly one lane, one slot matches)
        if (bj == base)            v0 = 1e30f;
        else if (bj == base + 64)  v1 = 1e30f;
        else if (bj == base + 128) v2 = 1e30f;
        else if (bj == base + 192) v3 = 1e30f;
    }
    if (ln < KNN) { candv[wv * KNN + ln] = selv; candj[wv * KNN + ln] = seli; }
    __syncthreads();

    // ---- phase 2: wave 0 merges 4 x 32 -> global top-32 ----
    if (wv == 0) {
        float c0v = candv[ln];      int c0j = candj[ln];
        float c1v = candv[64 + ln]; int c1j = candj[64 + ln];
        float fv = 0.0f; int fj = 0;
        for (int k = 0; k < KNN; k++) {
            float bv; int bj;
            if (c0v < c1v || (c0v == c1v && c0j < c1j)) { bv = c0v; bj = c0j; }
            else                                        { bv = c1v; bj = c1j; }
#pragma unroll
            for (int off = 1; off < 64; off <<= 1) {
                float ov = __shfl_xor(bv, off);
                int   oj = __shfl_xor(bj, off);
                if (ov < bv || (ov == bv && oj < bj)) { bv = ov; bj = oj; }
            }
            if (ln == k) { fv = bv; fj = bj; }
            if (bj == c0j) c0v = 1e30f;   // j unique per row -> safe eviction
            if (bj == c1j) c1v = 1e30f;
        }
        if (ln < KNN) {
            size_t o = (size_t)row * KNN + ln;
            out_d[o]     = fv;
            out_idx_f[o] = (float)fj;
            eidx[o]      = fj;
        }
    }
}

// ---------------- kernel 2.5: W -> bf16 fragment layout ----------------
// Wfrag[kt][n16][lane][8] : k = kt*32 + (lane>>4)*8 + j, col = n16*16 + (lane&15)
__global__ __launch_bounds__(256) void k_wprep(const float* __restrict__ W,
                                               ushort* __restrict__ wf)
{
    int x = blockIdx.x * 256 + threadIdx.x;
    if (x >= NKT * 8 * 64) return;
    int l = x & 63;
    int n16 = (x >> 6) & 7;
    int kt = x >> 9;
    int col = n16 * 16 + (l & 15);
    int kb  = kt * 32 + (l >> 4) * 8;
    ushort v[8];
#pragma unroll
    for (int j = 0; j < 8; j++) {
        int k = kb + j;
        float f = (k < 1057) ? W[(size_t)k * EC + col] : 0.0f;
        v[j] = f2bf(f);
    }
    *(uint4*)&wf[(size_t)x * 8] = *(uint4*)&v[0];
}

// ---------------- kernel 3: MFMA edge GEMM + LayerNorm (F double-buffered) ----------------
__global__ __launch_bounds__(256) void k_edge(
    const float* __restrict__ atoms15, const int* __restrict__ eidx,
    const int* __restrict__ resi, const int* __restrict__ asym,
    const float* __restrict__ tbonds, const int* __restrict__ islig,
    const float* __restrict__ posW, const float* __restrict__ posb,
    const ushort* __restrict__ wfrag, const float* __restrict__ gamma_,
    const float* __restrict__ beta_, float* __restrict__ outE)
{
    __shared__ int   nb[64];
    __shared__ float tbv[64];
    __shared__ float Crow[2][45];
    __shared__ float Brow[64][45];
    __shared__ float epos[64][16];
    __shared__ float Dp[64][PP];
    __shared__ __attribute__((aligned(16))) ushort F[2][64][72];   // dbuf, stride 144B
    __shared__ float part[2][64][2];

    int blk = blockIdx.x;          // 1024 blocks, 2 KNN rows each
    int row0 = blk * 2;
    int b = row0 >> 10;
    int t = threadIdx.x;

    if (t < 64) nb[t] = eidx[(size_t)row0 * KNN + t];
    __syncthreads();

    if (t < 90) {
        int e = t / 45, r = t - e * 45;
        Crow[e][r] = atoms15[((size_t)(row0 + e)) * 45 + r];
    }
    {   // neighbor atoms: thread t -> edge t&63, atom chunk (t>>6)*12..+11
        int e = t & 63;
        const float* src = atoms15 + ((size_t)(b * NN) + nb[e]) * 45;
#pragma unroll
        for (int q = 0; q < 12; q++) {
            int r = (t >> 6) * 12 + q;
            if (r < 45) Brow[e][r] = src[r];
        }
    }
    for (int x = t; x < 64 * 16; x += 256) {   // positional features
        int e = x >> 4, r = x & 15;
        int ri = row0 + (e >> 5);
        int ii = ri & (NN - 1);
        int j = nb[e];
        int off = resi[(b << 10) + ii] - resi[(b << 10) + j];
        bool same = (asym[(b << 10) + ii] == asym[(b << 10) + j]);
        int d = same ? min(max(off + 32, 0), 64) : 65;
        epos[e][r] = posW[d * 16 + r] + posb[r];
    }
    if (t < 64) {
        int ri = row0 + (t >> 5);
        int ii = ri & (NN - 1);
        int j = nb[t];
        bool lg = (islig[(b << 10) + ii] != 0) || (islig[(b << 10) + j] != 0);
        tbv[t] = lg ? tbonds[((size_t)((b << 10) + ii)) * NN + j] : 0.0f;
    }
    __syncthreads();

    // pair distances: 64 edges x 65 pairs
    for (int x = t; x < 64 * PP; x += 256) {
        int e = x / PP, p = x - e * PP;
        int s, dd;
        if (p < 25) { s = p / 5; dd = p - s * 5; }
        else { int q = p - 25; s = q / 10; dd = 5 + (q - s * 10); }
        int cc = e >> 5;
        float dx = Crow[cc][s * 3 + 0] - Brow[e][dd * 3 + 0];
        float dy = Crow[cc][s * 3 + 1] - Brow[e][dd * 3 + 1];
        float dz = Crow[cc][s * 3 + 2] - Brow[e][dd * 3 + 2];
        Dp[e][p] = sqrtf(dx * dx + dy * dy + dz * dz + 1e-6f);
    }
    __syncthreads();

    const int l  = t & 63;
    const int w  = t >> 6;
    const int wm = w >> 1, wn = w & 1;
    const int lc = l & 15, g = l >> 4;

    f32x4 acc[2][4] = {};

    // stage chunk cs (features cs*64 + w*16 .. +15 for all 64 edges) into F[buf]
    auto STAGE = [&](int cs, int buf) {
        int e = l;          // edge = lane
        int fb = w;         // feature block = wave (wave-uniform branch)
        float vals[16];
        if (cs == 0 && fb == 0) {
#pragma unroll
            for (int i2 = 0; i2 < 16; i2++) vals[i2] = epos[e][i2];
        } else if (cs == 16 && fb >= 2) {
#pragma unroll
            for (int i2 = 0; i2 < 16; i2++) vals[i2] = 0.0f;
            if (fb == 2) vals[0] = tbv[e];
        } else {
            int p = 4 * cs + fb - 1;
            float d = Dp[e][p];
#pragma unroll
            for (int i2 = 0; i2 < 16; i2++) {
                float u = (d - (2.0f + (float)i2 * (20.0f / 15.0f))) * 0.8f;
                vals[i2] = __expf(-u * u);
            }
        }
        ushort us[16];
#pragma unroll
        for (int i2 = 0; i2 < 16; i2++) us[i2] = f2bf(vals[i2]);
        *(uint4*)&F[buf][e][fb * 16]     = *(uint4*)&us[0];
        *(uint4*)&F[buf][e][fb * 16 + 8] = *(uint4*)&us[8];
    };

    STAGE(0, 0);
    __syncthreads();

    for (int c = 0; c < NCHUNK; c++) {
        int cur = c & 1;
        if (c + 1 < NCHUNK) STAGE(c + 1, cur ^ 1);   // overlaps with MFMA below

        // ---- MFMA over the 64-feature chunk (2 k-steps of 32) ----
#pragma unroll
        for (int ks = 0; ks < 2; ks++) {
            bf16x8 a0 = *(const bf16x8*)&F[cur][wm * 32 + lc][ks * 32 + 8 * g];
            bf16x8 a1 = *(const bf16x8*)&F[cur][wm * 32 + 16 + lc][ks * 32 + 8 * g];
            int kt = c * 2 + ks;
#pragma unroll
            for (int ni = 0; ni < 4; ni++) {
                bf16x8 bfg = *(const bf16x8*)&wfrag[(((size_t)kt * 8 + wn * 4 + ni) * 64 + l) * 8];
                acc[0][ni] = __builtin_amdgcn_mfma_f32_16x16x32_bf16(a0, bfg, acc[0][ni], 0, 0, 0);
                acc[1][ni] = __builtin_amdgcn_mfma_f32_16x16x32_bf16(a1, bfg, acc[1][ni], 0, 0, 0);
            }
        }
        __syncthreads();   // next-chunk staging complete + this chunk's reads done
    }

    // ---- LayerNorm epilogue ----
    float gv[4], bev[4];
#pragma unroll
    for (int ni = 0; ni < 4; ni++) {
        int col = wn * 64 + ni * 16 + lc;
        gv[ni]  = gamma_[col];
        bev[ni] = beta_[col];
    }
#pragma unroll
    for (int mi = 0; mi < 2; mi++)
#pragma unroll
        for (int reg = 0; reg < 4; reg++) {
            float s = 0.0f, q = 0.0f;
#pragma unroll
            for (int ni = 0; ni < 4; ni++) {
                float v = acc[mi][ni][reg];
                s += v; q += v * v;
            }
#pragma unroll
            for (int m = 1; m < 16; m <<= 1) {
                s += __shfl_xor(s, m);
                q += __shfl_xor(q, m);
            }
            int srow = wm * 32 + mi * 16 + g * 4 + reg;
            if (lc == 0) { part[wn][srow][0] = s; part[wn][srow][1] = q; }
        }
    __syncthreads();
#pragma unroll
    for (int mi = 0; mi < 2; mi++)
#pragma unroll
        for (int reg = 0; reg < 4; reg++) {
            int srow = wm * 32 + mi * 16 + g * 4 + reg;
            float s = part[0][srow][0] + part[1][srow][0];
            float q = part[0][srow][1] + part[1][srow][1];
            float mu  = s * (1.0f / 128.0f);
            float var = q * (1.0f / 128.0f) - mu * mu;
            float rstd = rsqrtf(var + 1e-5f);
            size_t obase = ((size_t)blk * 64 + srow) * EC;
#pragma unroll
            for (int ni = 0; ni < 4; ni++) {
                float v = (acc[mi][ni][reg] - mu) * rstd * gv[ni] + bev[ni];
                outE[obase + wn * 64 + ni * 16 + lc] = v;
            }
        }
}

extern "C" void kernel_launch(void* const* d_in, const int* in_sizes, int n_in,
                              void* d_out, int out_size, void* d_ws, size_t ws_size,
                              hipStream_t stream)
{
    const float* coords = (const float*)d_in[0];
    const float* cond   = (const float*)d_in[1];
    const float* noise  = (const float*)d_in[2];
    const int*   resi   = (const int*)d_in[3];
    const int*   asym   = (const int*)d_in[4];
    const float* tbonds = (const float*)d_in[5];
    const int*   islig  = (const int*)d_in[6];
    const float* posW   = (const float*)d_in[7];
    const float* posb   = (const float*)d_in[8];
    const float* edgeW  = (const float*)d_in[9];
    const float* gamma_ = (const float*)d_in[10];
    const float* beta_  = (const float*)d_in[11];

    float* outE   = (float*)d_out;                          // (B,N,K,128)
    float* outIdx = outE + (size_t)BB * NN * KNN * EC;      // (B,N,K) as float
    float* outD   = outIdx + (size_t)BB * NN * KNN;         // (B,N,K)

    float*  atoms15 = (float*)d_ws;                                          // 368640 B
    int*    eidx    = (int*)((char*)d_ws + 368640);                          // 262144 B
    ushort* wfrag   = (ushort*)((char*)d_ws + 368640 + 262144);              // 278528 B

    k_wprep<<<(NKT * 8 * 64 + 255) / 256, 256, 0, stream>>>(edgeW, wfrag);
    k_atoms<<<(BB * NN + 255) / 256, 256, 0, stream>>>(coords, cond, noise, atoms15);
    k_knn<<<BB * NN, 256, 0, stream>>>(atoms15, cond, outIdx, outD, eidx);
    k_edge<<<BB * NN / 2, 256, 0, stream>>>(atoms15, eidx, resi, asym, tbonds, islig,
                                            posW, posb, wfrag, gamma_, beta_, outE);
}

// Round 10
// 196.804 us; speedup vs baseline: 3.3454x; 1.1881x over previous
//
#include <hip/hip_runtime.h>
#include <math.h>

#define BB 2
#define NN 1024
#define KNN 32
#define PP 65
#define NRBF 16
#define EC 128
#define KPAD 1088            // 17 chunks * 64
#define NCHUNK 17
#define NKT 34               // KPAD / 32 MFMA k-steps

typedef __attribute__((ext_vector_type(8))) short bf16x8;
typedef __attribute__((ext_vector_type(4))) float f32x4;

__device__ __forceinline__ ushort f2bf(float f) {
    union { float f; unsigned u; } v; v.f = f;
    unsigned r = v.u + 0x7fffu + ((v.u >> 16) & 1u);
    return (ushort)(r >> 16);
}

// ---------------- kernel 1: atoms15 ----------------
__global__ __launch_bounds__(256) void k_atoms(
    const float* __restrict__ coords, const float* __restrict__ mask,
    const float* __restrict__ noise, float* __restrict__ atoms15)
{
    int idx = blockIdx.x * blockDim.x + threadIdx.x;
    if (idx >= BB * NN) return;
    const float* c  = coords + (size_t)idx * 42;
    const float* nz = noise  + (size_t)idx * 42;
    const float* m  = mask   + (size_t)idx * 14;

    float X[14][3];
    float x1[3];
#pragma unroll
    for (int d = 0; d < 3; d++) x1[d] = c[3 + d] + nz[3 + d];
#pragma unroll
    for (int a = 0; a < 14; a++) {
        bool mm = m[a] > 0.0f;
#pragma unroll
        for (int d = 0; d < 3; d++) {
            float v = c[a * 3 + d] + nz[a * 3 + d];
            X[a][d] = mm ? v : x1[d];
        }
    }
    float bv[3], cv[3], av[3], cb[3];
#pragma unroll
    for (int d = 0; d < 3; d++) { bv[d] = X[1][d] - X[0][d]; cv[d] = X[2][d] - X[1][d]; }
    av[0] = bv[1] * cv[2] - bv[2] * cv[1];
    av[1] = bv[2] * cv[0] - bv[0] * cv[2];
    av[2] = bv[0] * cv[1] - bv[1] * cv[0];
#pragma unroll
    for (int d = 0; d < 3; d++)
        cb[d] = -0.58273431f * av[d] + 0.56802827f * bv[d] - 0.54067466f * cv[d] + X[1][d];

    float* o = atoms15 + (size_t)idx * 45;
#pragma unroll
    for (int a = 0; a < 4; a++)
#pragma unroll
        for (int d = 0; d < 3; d++) o[a * 3 + d] = X[a][d];
#pragma unroll
    for (int d = 0; d < 3; d++) o[4 * 3 + d] = cb[d];
#pragma unroll
    for (int a = 0; a < 10; a++)
#pragma unroll
        for (int d = 0; d < 3; d++) o[(5 + a) * 3 + d] = X[4 + a][d];
}

// ---------------- kernel 2: KNN, one wave per row ----------------
// Row's 1024 distances live in 16 regs/lane; 32 argmin rounds with in-lane
// 16-way tree + 6-step butterfly; register-predicated eviction (static
// indices, no LDS writes in the loop). No phase-2 merge, no idle waves.
__global__ __launch_bounds__(256) void k_knn(
    const float* __restrict__ atoms15, const float* __restrict__ cond,
    float* __restrict__ out_idx_f, float* __restrict__ out_d, int* __restrict__ eidx)
{
    __shared__ float CAx[NN], CAy[NN], CAz[NN], CAw[NN];   // 16 KB/block

    int t = threadIdx.x;
    int ln = t & 63, w = t >> 6;
    int row0 = blockIdx.x * 4;          // 512 blocks x 4 rows (same batch b)
    int b = row0 >> 10;

    for (int j = t; j < NN; j += 256) {
        const float* aj = atoms15 + ((size_t)b * NN + j) * 45;
        CAx[j] = aj[3]; CAy[j] = aj[4]; CAz[j] = aj[5];
        CAw[j] = cond[((size_t)b * NN + j) * 14 + 1];
    }
    __syncthreads();

    int row = row0 + w;
    int i = row & (NN - 1);
    float mx = CAx[i], my = CAy[i], mz = CAz[i], mi = CAw[i];

    // 16 distances per lane (j = ln + 64q), row max via one butterfly
    float v[16];
    float lmax = -1e30f;
#pragma unroll
    for (int q = 0; q < 16; q++) {
        int j = ln + 64 * q;
        float dx = mx - CAx[j], dy = my - CAy[j], dz = mz - CAz[j];
        float m2 = mi * CAw[j];
        float D = m2 * sqrtf(dx * dx + dy * dy + dz * dz + 1e-6f);
        v[q] = D;
        lmax = fmaxf(lmax, D);
    }
#pragma unroll
    for (int off = 32; off > 0; off >>= 1) lmax = fmaxf(lmax, __shfl_xor(lmax, off));
#pragma unroll
    for (int q = 0; q < 16; q++) {
        float m2 = mi * CAw[ln + 64 * q];
        v[q] += (1.0f - m2) * lmax;
    }

    // 32 argmin rounds
    float selv = 0.0f; int selj = 0;
    for (int k = 0; k < KNN; k++) {
        // in-lane argmin; ascending q + strict < => lowest j wins ties
        float bv = v[0]; int bq = 0;
#pragma unroll
        for (int q = 1; q < 16; q++) {
            if (v[q] < bv) { bv = v[q]; bq = q; }
        }
        int bj = ln + (bq << 6);
#pragma unroll
        for (int off = 1; off < 64; off <<= 1) {
            float ov = __shfl_xor(bv, off);
            int   oj = __shfl_xor(bj, off);
            if (ov < bv || (ov == bv && oj < bj)) { bv = ov; bj = oj; }
        }
        if (ln == k) { selv = bv; selj = bj; }
        // eviction: only the owning lane matches one static slot
#pragma unroll
        for (int q = 0; q < 16; q++) {
            if (bj == ln + (q << 6)) v[q] = 1e30f;
        }
    }
    if (ln < KNN) {
        size_t o = (size_t)row * KNN + ln;
        out_d[o]     = selv;
        out_idx_f[o] = (float)selj;
        eidx[o]      = selj;
    }
}

// ---------------- kernel 2.5: W -> bf16 fragment layout ----------------
// Wfrag[kt][n16][lane][8] : k = kt*32 + (lane>>4)*8 + j, col = n16*16 + (lane&15)
__global__ __launch_bounds__(256) void k_wprep(const float* __restrict__ W,
                                               ushort* __restrict__ wf)
{
    int x = blockIdx.x * 256 + threadIdx.x;
    if (x >= NKT * 8 * 64) return;
    int l = x & 63;
    int n16 = (x >> 6) & 7;
    int kt = x >> 9;
    int col = n16 * 16 + (l & 15);
    int kb  = kt * 32 + (l >> 4) * 8;
    ushort v[8];
#pragma unroll
    for (int j = 0; j < 8; j++) {
        int k = kb + j;
        float f = (k < 1057) ? W[(size_t)k * EC + col] : 0.0f;
        v[j] = f2bf(f);
    }
    *(uint4*)&wf[(size_t)x * 8] = *(uint4*)&v[0];
}

// ---------------- kernel 3: MFMA edge GEMM + LayerNorm (F double-buffered) ----------------
__global__ __launch_bounds__(256) void k_edge(
    const float* __restrict__ atoms15, const int* __restrict__ eidx,
    const int* __restrict__ resi, const int* __restrict__ asym,
    const float* __restrict__ tbonds, const int* __restrict__ islig,
    const float* __restrict__ posW, const float* __restrict__ posb,
    const ushort* __restrict__ wfrag, const float* __restrict__ gamma_,
    const float* __restrict__ beta_, float* __restrict__ outE)
{
    __shared__ int   nb[64];
    __shared__ float tbv[64];
    __shared__ float Crow[2][45];
    __shared__ float Brow[64][45];
    __shared__ float epos[64][16];
    __shared__ float Dp[64][PP];
    __shared__ __attribute__((aligned(16))) ushort F[2][64][72];   // dbuf, stride 144B
    __shared__ float part[2][64][2];

    int blk = blockIdx.x;          // 1024 blocks, 2 KNN rows each
    int row0 = blk * 2;
    int b = row0 >> 10;
    int t = threadIdx.x;

    if (t < 64) nb[t] = eidx[(size_t)row0 * KNN + t];
    __syncthreads();

    if (t < 90) {
        int e = t / 45, r = t - e * 45;
        Crow[e][r] = atoms15[((size_t)(row0 + e)) * 45 + r];
    }
    {   // neighbor atoms: thread t -> edge t&63, atom chunk (t>>6)*12..+11
        int e = t & 63;
        const float* src = atoms15 + ((size_t)(b * NN) + nb[e]) * 45;
#pragma unroll
        for (int q = 0; q < 12; q++) {
            int r = (t >> 6) * 12 + q;
            if (r < 45) Brow[e][r] = src[r];
        }
    }
    for (int x = t; x < 64 * 16; x += 256) {   // positional features
        int e = x >> 4, r = x & 15;
        int ri = row0 + (e >> 5);
        int ii = ri & (NN - 1);
        int j = nb[e];
        int off = resi[(b << 10) + ii] - resi[(b << 10) + j];
        bool same = (asym[(b << 10) + ii] == asym[(b << 10) + j]);
        int d = same ? min(max(off + 32, 0), 64) : 65;
        epos[e][r] = posW[d * 16 + r] + posb[r];
    }
    if (t < 64) {
        int ri = row0 + (t >> 5);
        int ii = ri & (NN - 1);
        int j = nb[t];
        bool lg = (islig[(b << 10) + ii] != 0) || (islig[(b << 10) + j] != 0);
        tbv[t] = lg ? tbonds[((size_t)((b << 10) + ii)) * NN + j] : 0.0f;
    }
    __syncthreads();

    // pair distances: 64 edges x 65 pairs
    for (int x = t; x < 64 * PP; x += 256) {
        int e = x / PP, p = x - e * PP;
        int s, dd;
        if (p < 25) { s = p / 5; dd = p - s * 5; }
        else { int q = p - 25; s = q / 10; dd = 5 + (q - s * 10); }
        int cc = e >> 5;
        float dx = Crow[cc][s * 3 + 0] - Brow[e][dd * 3 + 0];
        float dy = Crow[cc][s * 3 + 1] - Brow[e][dd * 3 + 1];
        float dz = Crow[cc][s * 3 + 2] - Brow[e][dd * 3 + 2];
        Dp[e][p] = sqrtf(dx * dx + dy * dy + dz * dz + 1e-6f);
    }
    __syncthreads();

    const int l  = t & 63;
    const int w  = t >> 6;
    const int wm = w >> 1, wn = w & 1;
    const int lc = l & 15, g = l >> 4;

    f32x4 acc[2][4] = {};

    // stage chunk cs (features cs*64 + w*16 .. +15 for all 64 edges) into F[buf]
    auto STAGE = [&](int cs, int buf) {
        int e = l;          // edge = lane
        int fb = w;         // feature block = wave (wave-uniform branch)
        float vals[16];
        if (cs == 0 && fb == 0) {
#pragma unroll
            for (int i2 = 0; i2 < 16; i2++) vals[i2] = epos[e][i2];
        } else if (cs == 16 && fb >= 2) {
#pragma unroll
            for (int i2 = 0; i2 < 16; i2++) vals[i2] = 0.0f;
            if (fb == 2) vals[0] = tbv[e];
        } else {
            int p = 4 * cs + fb - 1;
            float d = Dp[e][p];
#pragma unroll
            for (int i2 = 0; i2 < 16; i2++) {
                float u = (d - (2.0f + (float)i2 * (20.0f / 15.0f))) * 0.8f;
                vals[i2] = __expf(-u * u);
            }
        }
        ushort us[16];
#pragma unroll
        for (int i2 = 0; i2 < 16; i2++) us[i2] = f2bf(vals[i2]);
        *(uint4*)&F[buf][e][fb * 16]     = *(uint4*)&us[0];
        *(uint4*)&F[buf][e][fb * 16 + 8] = *(uint4*)&us[8];
    };

    STAGE(0, 0);
    __syncthreads();

    for (int c = 0; c < NCHUNK; c++) {
        int cur = c & 1;
        if (c + 1 < NCHUNK) STAGE(c + 1, cur ^ 1);   // overlaps with MFMA below

        // ---- MFMA over the 64-feature chunk (2 k-steps of 32) ----
#pragma unroll
        for (int ks = 0; ks < 2; ks++) {
            bf16x8 a0 = *(const bf16x8*)&F[cur][wm * 32 + lc][ks * 32 + 8 * g];
            bf16x8 a1 = *(const bf16x8*)&F[cur][wm * 32 + 16 + lc][ks * 32 + 8 * g];
            int kt = c * 2 + ks;
#pragma unroll
            for (int ni = 0; ni < 4; ni++) {
                bf16x8 bfg = *(const bf16x8*)&wfrag[(((size_t)kt * 8 + wn * 4 + ni) * 64 + l) * 8];
                acc[0][ni] = __builtin_amdgcn_mfma_f32_16x16x32_bf16(a0, bfg, acc[0][ni], 0, 0, 0);
                acc[1][ni] = __builtin_amdgcn_mfma_f32_16x16x32_bf16(a1, bfg, acc[1][ni], 0, 0, 0);
            }
        }
        __syncthreads();   // next-chunk staging complete + this chunk's reads done
    }

    // ---- LayerNorm epilogue ----
    float gv[4], bev[4];
#pragma unroll
    for (int ni = 0; ni < 4; ni++) {
        int col = wn * 64 + ni * 16 + lc;
        gv[ni]  = gamma_[col];
        bev[ni] = beta_[col];
    }
#pragma unroll
    for (int mi = 0; mi < 2; mi++)
#pragma unroll
        for (int reg = 0; reg < 4; reg++) {
            float s = 0.0f, q = 0.0f;
#pragma unroll
            for (int ni = 0; ni < 4; ni++) {
                float v = acc[mi][ni][reg];
                s += v; q += v * v;
            }
#pragma unroll
            for (int m = 1; m < 16; m <<= 1) {
                s += __shfl_xor(s, m);
                q += __shfl_xor(q, m);
            }
            int srow = wm * 32 + mi * 16 + g * 4 + reg;
            if (lc == 0) { part[wn][srow][0] = s; part[wn][srow][1] = q; }
        }
    __syncthreads();
#pragma unroll
    for (int mi = 0; mi < 2; mi++)
#pragma unroll
        for (int reg = 0; reg < 4; reg++) {
            int srow = wm * 32 + mi * 16 + g * 4 + reg;
            float s = part[0][srow][0] + part[1][srow][0];
            float q = part[0][srow][1] + part[1][srow][1];
            float mu  = s * (1.0f / 128.0f);
            float var = q * (1.0f / 128.0f) - mu * mu;
            float rstd = rsqrtf(var + 1e-5f);
            size_t obase = ((size_t)blk * 64 + srow) * EC;
#pragma unroll
            for (int ni = 0; ni < 4; ni++) {
                float v = (acc[mi][ni][reg] - mu) * rstd * gv[ni] + bev[ni];
                outE[obase + wn * 64 + ni * 16 + lc] = v;
            }
        }
}

extern "C" void kernel_launch(void* const* d_in, const int* in_sizes, int n_in,
                              void* d_out, int out_size, void* d_ws, size_t ws_size,
                              hipStream_t stream)
{
    const float* coords = (const float*)d_in[0];
    const float* cond   = (const float*)d_in[1];
    const float* noise  = (const float*)d_in[2];
    const int*   resi   = (const int*)d_in[3];
    const int*   asym   = (const int*)d_in[4];
    const float* tbonds = (const float*)d_in[5];
    const int*   islig  = (const int*)d_in[6];
    const float* posW   = (const float*)d_in[7];
    const float* posb   = (const float*)d_in[8];
    const float* edgeW  = (const float*)d_in[9];
    const float* gamma_ = (const float*)d_in[10];
    const float* beta_  = (const float*)d_in[11];

    float* outE   = (float*)d_out;                          // (B,N,K,128)
    float* outIdx = outE + (size_t)BB * NN * KNN * EC;      // (B,N,K) as float
    float* outD   = outIdx + (size_t)BB * NN * KNN;         // (B,N,K)

    float*  atoms15 = (float*)d_ws;                                          // 368640 B
    int*    eidx    = (int*)((char*)d_ws + 368640);                          // 262144 B
    ushort* wfrag   = (ushort*)((char*)d_ws + 368640 + 262144);              // 278528 B

    k_wprep<<<(NKT * 8 * 64 + 255) / 256, 256, 0, stream>>>(edgeW, wfrag);
    k_atoms<<<(BB * NN + 255) / 256, 256, 0, stream>>>(coords, cond, noise, atoms15);
    k_knn<<<BB * NN / 4, 256, 0, stream>>>(atoms15, cond, outIdx, outD, eidx);
    k_edge<<<BB * NN / 2, 256, 0, stream>>>(atoms15, eidx, resi, asym, tbonds, islig,
                                            posW, posb, wfrag, gamma_, beta_, outE);
}